// Round 13
// baseline (73.274 us; speedup 1.0000x reference)
//
#include <hip/hip_runtime.h>

// AttnMap (algebra verified rounds 1-12):
//   Mt[bt][f][ch] = sum_q dec[b, q*16+t, ch] * W[q*8 + (ch>>5)][f]
//   out[bt][s][f] = relu( sum_ch enc[bt][s][ch] * Mt[f][ch] + bias[f] )
// R13 = R11 (best, 58.26us) with ONE change: output stores are normal
// (cacheable) instead of nontemporal. In replay steady state the output
// region is rewritten every call; letting it allocate in L2/L3 avoids the
// forced 131 MB HBM write drain per replay.

#define CCH 256
#define FF  256
#define HW  1024

typedef __bf16 bf16x8 __attribute__((ext_vector_type(8)));
typedef float  f32x4  __attribute__((ext_vector_type(4)));
typedef float  f32x16 __attribute__((ext_vector_type(16)));
typedef unsigned short u16x4 __attribute__((ext_vector_type(4)));
typedef unsigned short u16x8 __attribute__((ext_vector_type(8)));

__device__ __forceinline__ unsigned short f2bf(float f) {
    __bf16 b = (__bf16)f;
    return __builtin_bit_cast(unsigned short, b);
}

__device__ __forceinline__ void gload_lds16(const unsigned short* g, unsigned short* l) {
    __builtin_amdgcn_global_load_lds(
        (const __attribute__((address_space(1))) unsigned int*)g,
        (__attribute__((address_space(3))) unsigned int*)l, 16, 0, 0);
}

// ---------------- Phase 1: Mt[bt][f][ch] (bf16, f-major) — verified R5 ----------------
__global__ __launch_bounds__(256) void compute_Mt_kernel(
        const float* __restrict__ dec, const float* __restrict__ W,
        unsigned short* __restrict__ Mt) {
    const int j  = blockIdx.x;            // g-pair: g = 2j, 2j+1
    const int bt = blockIdx.y;
    const int b  = bt >> 4, t = bt & 15;
    const int f  = threadIdx.x;
    __shared__ float ldec[16][64];        // 16 q x 64 ch (this g-pair)

    const float* decbt = dec + (size_t)b * 65536 + (size_t)t * 256 + j * 64;
    {
        const int q = threadIdx.x >> 4, seg = threadIdx.x & 15;
        const float4 v = *reinterpret_cast<const float4*>(decbt + q * 4096 + seg * 4);
        *reinterpret_cast<float4*>(&ldec[q][seg * 4]) = v;
    }
    __syncthreads();

    u16x8 rv[8];
    #pragma unroll
    for (int gi = 0; gi < 2; ++gi) {
        const int g = j * 2 + gi;
        float wv[16];
        #pragma unroll
        for (int q = 0; q < 16; ++q) wv[q] = W[(q * 8 + g) * FF + f];   // coalesced
        #pragma unroll
        for (int cc = 0; cc < 32; ++cc) {
            float s = 0.f;
            #pragma unroll
            for (int q = 0; q < 16; ++q) s += ldec[q][gi * 32 + cc] * wv[q];
            const int idx = gi * 32 + cc;
            rv[idx >> 3][idx & 7] = f2bf(s);
        }
    }
    unsigned short* dst = Mt + (size_t)bt * (FF * CCH) + (size_t)f * CCH + j * 64;
    #pragma unroll
    for (int s = 0; s < 8; ++s)
        *reinterpret_cast<u16x8*>(dst + s * 8) = rv[s];   // 128 B/thread contiguous
}

// ---------------- Phase 2: tiled MFMA GEMM, 256 rows x 128 f per block ----------------
// 1024 blocks x 512 thr (8 waves). Each wave: 32 rows x 128 f, 8 k-steps.
__global__ __launch_bounds__(512, 4) void gemm_tile_kernel(
        const float* __restrict__ E, const unsigned short* __restrict__ Mt,
        const float* __restrict__ bias, float* __restrict__ O) {
    const int id0 = blockIdx.x;                       // 0..1023
    const int id  = ((id0 & 7) << 7) | (id0 >> 3);    // XCD-chunked bijection
    const int bt = id >> 3;                           // 8 ids per bt
    const int fh = (id >> 2) & 1;                     // 128-f half
    const int rg = id & 3;                            // 256-row group
    const int tid = threadIdx.x;
    const int lane = tid & 63, wq = tid >> 6;         // wq 0..7
    const int lr5 = lane & 31, kgr = lane >> 5;

    const float*          Ebt = E  + (size_t)bt * (HW * CCH);
    const unsigned short* Mtb = Mt + (size_t)bt * (FF * CCH) + (size_t)(fh * 128) * CCH;
    float*                Obt = O  + (size_t)bt * (HW * FF);

    __shared__ __align__(16) unsigned short Bs[128 * 256];  // 64 KB, shared by 8 waves
    __shared__ __align__(16) unsigned short Et[8][32 * 32]; // 8 x 2KB wave-private

    // ---- stage Bs: linear LDS dest, XOR on the GLOBAL source (rule #21) ----
    #pragma unroll
    for (int p = 0; p < 8; ++p) {
        const int g = p * 512 + tid;                  // 16B granule index, 0..4095
        const int r = g >> 5, s = g & 31;             // f-row, slot
        gload_lds16(Mtb + (size_t)r * CCH + ((s ^ (r & 7)) * 8), &Bs[g * 8]);
    }
    __syncthreads();

    // ---- main loop (R10 schedule), 32 rows/wave, 8 k-steps, 4 fn ----
    const int rowbase = rg * 256 + wq * 32;

    float bv[4];
    #pragma unroll
    for (int fn = 0; fn < 4; ++fn) bv[fn] = bias[fh * 128 + fn * 32 + lr5];

    const int g_r8 = lane >> 3;                       // staging row-in-8
    const int g_s3 = lane & 7;                        // staging 16B slot
    const int bswz = lr5 & 7;                         // Bs read swizzle
    const int eswz = lr5 & 3;                         // E-tile read swizzle
    const unsigned short* Bsp[4];
    #pragma unroll
    for (int fn = 0; fn < 4; ++fn) Bsp[fn] = &Bs[(fn * 32 + lr5) * 256];
    unsigned short* Etw = &Et[wq][0];
    const unsigned short* Etr = &Etw[lr5 * 32];

    f32x4 Sva[4], Svb[4];
    f32x16 acc0, acc1, acc2, acc3;

    auto GLOAD = [&](int it, f32x4 (&S)[4]) {         // full 128B-line loads
        const float* base = Ebt + (size_t)rowbase * CCH + (it & 7) * 32 + g_s3 * 4;
        #pragma unroll
        for (int i = 0; i < 4; ++i)
            S[i] = *reinterpret_cast<const f32x4*>(base + (size_t)(i * 8 + g_r8) * CCH);
    };
    auto EWRITE = [&](const f32x4 (&S)[4]) {          // cvt + swizzled ds_write_b64
        #pragma unroll
        for (int i = 0; i < 4; ++i) {
            const int r = i * 8 + g_r8;
            u16x4 h = { f2bf(S[i][0]), f2bf(S[i][1]), f2bf(S[i][2]), f2bf(S[i][3]) };
            *reinterpret_cast<u16x4*>(
                &Etw[r * 32 + (((g_s3 >> 1) ^ (r & 3)) * 8) + (g_s3 & 1) * 4]) = h;
        }
    };
    auto COMPUTE = [&](int it) {
        const int kc = it & 7;
        if (kc == 0) {
            acc0 = (f32x16)0.f; acc1 = (f32x16)0.f;
            acc2 = (f32x16)0.f; acc3 = (f32x16)0.f;
        }
        #pragma unroll
        for (int kk = 0; kk < 2; ++kk) {
            const bf16x8 af = *reinterpret_cast<const bf16x8*>(
                &Etr[((kk * 2 + kgr) ^ eswz) * 8]);
            const int bo = ((kc * 4 + kk * 2 + kgr) ^ bswz) * 8;
            acc0 = __builtin_amdgcn_mfma_f32_32x32x16_bf16(
                af, *reinterpret_cast<const bf16x8*>(&Bsp[0][bo]), acc0, 0, 0, 0);
            acc1 = __builtin_amdgcn_mfma_f32_32x32x16_bf16(
                af, *reinterpret_cast<const bf16x8*>(&Bsp[1][bo]), acc1, 0, 0, 0);
            acc2 = __builtin_amdgcn_mfma_f32_32x32x16_bf16(
                af, *reinterpret_cast<const bf16x8*>(&Bsp[2][bo]), acc2, 0, 0, 0);
            acc3 = __builtin_amdgcn_mfma_f32_32x32x16_bf16(
                af, *reinterpret_cast<const bf16x8*>(&Bsp[3][bo]), acc3, 0, 0, 0);
        }
        if (kc == 7) {
            // C/D: col = lane&31, row = (reg&3) + 8*(reg>>2) + 4*(lane>>5)
            const int row0 = rowbase + 4 * kgr;
            #pragma unroll
            for (int reg = 0; reg < 16; ++reg) {
                const int r = row0 + (reg & 3) + 8 * (reg >> 2);
                float* op = Obt + (size_t)r * FF + fh * 128 + lr5;
                op[0]  = fmaxf(acc0[reg] + bv[0], 0.f);   // cacheable stores (R13)
                op[32] = fmaxf(acc1[reg] + bv[1], 0.f);
                op[64] = fmaxf(acc2[reg] + bv[2], 0.f);
                op[96] = fmaxf(acc3[reg] + bv[3], 0.f);
            }
        }
    };

    GLOAD(0, Sva);
    GLOAD(1, Svb);
    EWRITE(Sva);                      // tile <- it 0
    for (int itp = 0; itp < 8; itp += 2) {
        COMPUTE(itp);                 // reads tile(itp)
        if (itp + 2 < 8) GLOAD(itp + 2, Sva);
        EWRITE(Svb);                  // tile <- itp+1 (after reads of itp)
        COMPUTE(itp + 1);
        if (itp + 3 < 8) GLOAD(itp + 3, Svb);
        if (itp + 2 < 8) EWRITE(Sva); // tile <- itp+2
    }
}

extern "C" void kernel_launch(void* const* d_in, const int* in_sizes, int n_in,
                              void* d_out, int out_size, void* d_ws, size_t ws_size,
                              hipStream_t stream) {
    const float* dec  = (const float*)d_in[0];   // (8, 256, 256)
    const float* enc  = (const float*)d_in[1];   // (8, 16, 32, 32, 256)
    const float* W    = (const float*)d_in[2];   // (128, 256)
    const float* bias = (const float*)d_in[3];   // (256,)
    float* out = (float*)d_out;                  // (8, 16, 32, 32, 256) fp32
    unsigned short* Mt = (unsigned short*)d_ws;  // 128*256*256*2 = 16.8 MB bf16

    compute_Mt_kernel<<<dim3(4, 128), dim3(256), 0, stream>>>(dec, W, Mt);
    gemm_tile_kernel<<<dim3(1024), dim3(512), 0, stream>>>(enc, Mt, bias, out);
}

// Round 14
// 58.262 us; speedup vs baseline: 1.2577x; 1.2577x over previous
//
#include <hip/hip_runtime.h>

// AttnMap (algebra verified rounds 1-13):
//   Mt[bt][f][ch] = sum_q dec[b, q*16+t, ch] * W[q*8 + (ch>>5)][f]
//   out[bt][s][f] = relu( sum_ch enc[bt][s][ch] * Mt[f][ch] + bias[f] )
// R14 = exact revert to R11 (measured best, 58.26us wall):
// 256 rows x 128 f blocks (8 waves; wave = 32 rows x 128 f).
// Bs = 64KB (128f x 256ch) staged via global_load_lds w/ source-XOR,
// Et = 16KB wave-private, 80KB LDS = 2 blocks/CU. Nontemporal output
// stores (R13 A/B proved cacheable stores regress: writes drain anyway).

#define CCH 256
#define FF  256
#define HW  1024

typedef __bf16 bf16x8 __attribute__((ext_vector_type(8)));
typedef float  f32x4  __attribute__((ext_vector_type(4)));
typedef float  f32x16 __attribute__((ext_vector_type(16)));
typedef unsigned short u16x4 __attribute__((ext_vector_type(4)));
typedef unsigned short u16x8 __attribute__((ext_vector_type(8)));

__device__ __forceinline__ unsigned short f2bf(float f) {
    __bf16 b = (__bf16)f;
    return __builtin_bit_cast(unsigned short, b);
}

__device__ __forceinline__ void gload_lds16(const unsigned short* g, unsigned short* l) {
    __builtin_amdgcn_global_load_lds(
        (const __attribute__((address_space(1))) unsigned int*)g,
        (__attribute__((address_space(3))) unsigned int*)l, 16, 0, 0);
}

// ---------------- Phase 1: Mt[bt][f][ch] (bf16, f-major) — verified R5 ----------------
__global__ __launch_bounds__(256) void compute_Mt_kernel(
        const float* __restrict__ dec, const float* __restrict__ W,
        unsigned short* __restrict__ Mt) {
    const int j  = blockIdx.x;            // g-pair: g = 2j, 2j+1
    const int bt = blockIdx.y;
    const int b  = bt >> 4, t = bt & 15;
    const int f  = threadIdx.x;
    __shared__ float ldec[16][64];        // 16 q x 64 ch (this g-pair)

    const float* decbt = dec + (size_t)b * 65536 + (size_t)t * 256 + j * 64;
    {
        const int q = threadIdx.x >> 4, seg = threadIdx.x & 15;
        const float4 v = *reinterpret_cast<const float4*>(decbt + q * 4096 + seg * 4);
        *reinterpret_cast<float4*>(&ldec[q][seg * 4]) = v;
    }
    __syncthreads();

    u16x8 rv[8];
    #pragma unroll
    for (int gi = 0; gi < 2; ++gi) {
        const int g = j * 2 + gi;
        float wv[16];
        #pragma unroll
        for (int q = 0; q < 16; ++q) wv[q] = W[(q * 8 + g) * FF + f];   // coalesced
        #pragma unroll
        for (int cc = 0; cc < 32; ++cc) {
            float s = 0.f;
            #pragma unroll
            for (int q = 0; q < 16; ++q) s += ldec[q][gi * 32 + cc] * wv[q];
            const int idx = gi * 32 + cc;
            rv[idx >> 3][idx & 7] = f2bf(s);
        }
    }
    unsigned short* dst = Mt + (size_t)bt * (FF * CCH) + (size_t)f * CCH + j * 64;
    #pragma unroll
    for (int s = 0; s < 8; ++s)
        *reinterpret_cast<u16x8*>(dst + s * 8) = rv[s];   // 128 B/thread contiguous
}

// ---------------- Phase 2: tiled MFMA GEMM, 256 rows x 128 f per block ----------------
// 1024 blocks x 512 thr (8 waves). Each wave: 32 rows x 128 f, 8 k-steps.
__global__ __launch_bounds__(512, 4) void gemm_tile_kernel(
        const float* __restrict__ E, const unsigned short* __restrict__ Mt,
        const float* __restrict__ bias, float* __restrict__ O) {
    const int id0 = blockIdx.x;                       // 0..1023
    const int id  = ((id0 & 7) << 7) | (id0 >> 3);    // XCD-chunked bijection
    const int bt = id >> 3;                           // 8 ids per bt
    const int fh = (id >> 2) & 1;                     // 128-f half
    const int rg = id & 3;                            // 256-row group
    const int tid = threadIdx.x;
    const int lane = tid & 63, wq = tid >> 6;         // wq 0..7
    const int lr5 = lane & 31, kgr = lane >> 5;

    const float*          Ebt = E  + (size_t)bt * (HW * CCH);
    const unsigned short* Mtb = Mt + (size_t)bt * (FF * CCH) + (size_t)(fh * 128) * CCH;
    float*                Obt = O  + (size_t)bt * (HW * FF);

    __shared__ __align__(16) unsigned short Bs[128 * 256];  // 64 KB, shared by 8 waves
    __shared__ __align__(16) unsigned short Et[8][32 * 32]; // 8 x 2KB wave-private

    // ---- stage Bs: linear LDS dest, XOR on the GLOBAL source (rule #21) ----
    #pragma unroll
    for (int p = 0; p < 8; ++p) {
        const int g = p * 512 + tid;                  // 16B granule index, 0..4095
        const int r = g >> 5, s = g & 31;             // f-row, slot
        gload_lds16(Mtb + (size_t)r * CCH + ((s ^ (r & 7)) * 8), &Bs[g * 8]);
    }
    __syncthreads();

    // ---- main loop (R10 schedule), 32 rows/wave, 8 k-steps, 4 fn ----
    const int rowbase = rg * 256 + wq * 32;

    float bv[4];
    #pragma unroll
    for (int fn = 0; fn < 4; ++fn) bv[fn] = bias[fh * 128 + fn * 32 + lr5];

    const int g_r8 = lane >> 3;                       // staging row-in-8
    const int g_s3 = lane & 7;                        // staging 16B slot
    const int bswz = lr5 & 7;                         // Bs read swizzle
    const int eswz = lr5 & 3;                         // E-tile read swizzle
    const unsigned short* Bsp[4];
    #pragma unroll
    for (int fn = 0; fn < 4; ++fn) Bsp[fn] = &Bs[(fn * 32 + lr5) * 256];
    unsigned short* Etw = &Et[wq][0];
    const unsigned short* Etr = &Etw[lr5 * 32];

    f32x4 Sva[4], Svb[4];
    f32x16 acc0, acc1, acc2, acc3;

    auto GLOAD = [&](int it, f32x4 (&S)[4]) {         // full 128B-line loads
        const float* base = Ebt + (size_t)rowbase * CCH + (it & 7) * 32 + g_s3 * 4;
        #pragma unroll
        for (int i = 0; i < 4; ++i)
            S[i] = *reinterpret_cast<const f32x4*>(base + (size_t)(i * 8 + g_r8) * CCH);
    };
    auto EWRITE = [&](const f32x4 (&S)[4]) {          // cvt + swizzled ds_write_b64
        #pragma unroll
        for (int i = 0; i < 4; ++i) {
            const int r = i * 8 + g_r8;
            u16x4 h = { f2bf(S[i][0]), f2bf(S[i][1]), f2bf(S[i][2]), f2bf(S[i][3]) };
            *reinterpret_cast<u16x4*>(
                &Etw[r * 32 + (((g_s3 >> 1) ^ (r & 3)) * 8) + (g_s3 & 1) * 4]) = h;
        }
    };
    auto COMPUTE = [&](int it) {
        const int kc = it & 7;
        if (kc == 0) {
            acc0 = (f32x16)0.f; acc1 = (f32x16)0.f;
            acc2 = (f32x16)0.f; acc3 = (f32x16)0.f;
        }
        #pragma unroll
        for (int kk = 0; kk < 2; ++kk) {
            const bf16x8 af = *reinterpret_cast<const bf16x8*>(
                &Etr[((kk * 2 + kgr) ^ eswz) * 8]);
            const int bo = ((kc * 4 + kk * 2 + kgr) ^ bswz) * 8;
            acc0 = __builtin_amdgcn_mfma_f32_32x32x16_bf16(
                af, *reinterpret_cast<const bf16x8*>(&Bsp[0][bo]), acc0, 0, 0, 0);
            acc1 = __builtin_amdgcn_mfma_f32_32x32x16_bf16(
                af, *reinterpret_cast<const bf16x8*>(&Bsp[1][bo]), acc1, 0, 0, 0);
            acc2 = __builtin_amdgcn_mfma_f32_32x32x16_bf16(
                af, *reinterpret_cast<const bf16x8*>(&Bsp[2][bo]), acc2, 0, 0, 0);
            acc3 = __builtin_amdgcn_mfma_f32_32x32x16_bf16(
                af, *reinterpret_cast<const bf16x8*>(&Bsp[3][bo]), acc3, 0, 0, 0);
        }
        if (kc == 7) {
            // C/D: col = lane&31, row = (reg&3) + 8*(reg>>2) + 4*(lane>>5)
            const int row0 = rowbase + 4 * kgr;
            #pragma unroll
            for (int reg = 0; reg < 16; ++reg) {
                const int r = row0 + (reg & 3) + 8 * (reg >> 2);
                float* op = Obt + (size_t)r * FF + fh * 128 + lr5;
                __builtin_nontemporal_store(fmaxf(acc0[reg] + bv[0], 0.f), op);
                __builtin_nontemporal_store(fmaxf(acc1[reg] + bv[1], 0.f), op + 32);
                __builtin_nontemporal_store(fmaxf(acc2[reg] + bv[2], 0.f), op + 64);
                __builtin_nontemporal_store(fmaxf(acc3[reg] + bv[3], 0.f), op + 96);
            }
        }
    };

    GLOAD(0, Sva);
    GLOAD(1, Svb);
    EWRITE(Sva);                      // tile <- it 0
    for (int itp = 0; itp < 8; itp += 2) {
        COMPUTE(itp);                 // reads tile(itp)
        if (itp + 2 < 8) GLOAD(itp + 2, Sva);
        EWRITE(Svb);                  // tile <- itp+1 (after reads of itp)
        COMPUTE(itp + 1);
        if (itp + 3 < 8) GLOAD(itp + 3, Svb);
        if (itp + 2 < 8) EWRITE(Sva); // tile <- itp+2
    }
}

extern "C" void kernel_launch(void* const* d_in, const int* in_sizes, int n_in,
                              void* d_out, int out_size, void* d_ws, size_t ws_size,
                              hipStream_t stream) {
    const float* dec  = (const float*)d_in[0];   // (8, 256, 256)
    const float* enc  = (const float*)d_in[1];   // (8, 16, 32, 32, 256)
    const float* W    = (const float*)d_in[2];   // (128, 256)
    const float* bias = (const float*)d_in[3];   // (256,)
    float* out = (float*)d_out;                  // (8, 16, 32, 32, 256) fp32
    unsigned short* Mt = (unsigned short*)d_ws;  // 128*256*256*2 = 16.8 MB bf16

    compute_Mt_kernel<<<dim3(4, 128), dim3(256), 0, stream>>>(dec, W, Mt);
    gemm_tile_kernel<<<dim3(1024), dim3(512), 0, stream>>>(enc, Mt, bias, out);
}

// Round 15
// 58.103 us; speedup vs baseline: 1.2611x; 1.0027x over previous
//
#include <hip/hip_runtime.h>

// AttnMap (algebra verified rounds 1-14):
//   Mt[bt][f][ch] = sum_q dec[b, q*16+t, ch] * W[q*8 + (ch>>5)][f]
//   out[bt][s][f] = relu( sum_ch enc[bt][s][ch] * Mt[f][ch] + bias[f] )
// R15 = R14 (58.26us, confirmed best) + split-K Bs staging with counted
// vmcnt barrier: Bs stored as [k-half][128 rows][16 slots]; issue order
// E(0,1) -> Bs-half1 -> Bs-half2 (sched_barrier pinned); then
// s_waitcnt vmcnt(4) + raw s_barrier -> waves start computing kc0..3 with
// half2 (32KB) still in flight. In-order vmcnt retirement (compiler's own
// GLOAD(2) dependency wait) guarantees half2 lands before kc4.

#define CCH 256
#define FF  256
#define HW  1024

typedef __bf16 bf16x8 __attribute__((ext_vector_type(8)));
typedef float  f32x4  __attribute__((ext_vector_type(4)));
typedef float  f32x16 __attribute__((ext_vector_type(16)));
typedef unsigned short u16x4 __attribute__((ext_vector_type(4)));
typedef unsigned short u16x8 __attribute__((ext_vector_type(8)));

__device__ __forceinline__ unsigned short f2bf(float f) {
    __bf16 b = (__bf16)f;
    return __builtin_bit_cast(unsigned short, b);
}

__device__ __forceinline__ void gload_lds16(const unsigned short* g, unsigned short* l) {
    __builtin_amdgcn_global_load_lds(
        (const __attribute__((address_space(1))) unsigned int*)g,
        (__attribute__((address_space(3))) unsigned int*)l, 16, 0, 0);
}

// ---------------- Phase 1: Mt[bt][f][ch] (bf16, f-major) — verified R5 ----------------
__global__ __launch_bounds__(256) void compute_Mt_kernel(
        const float* __restrict__ dec, const float* __restrict__ W,
        unsigned short* __restrict__ Mt) {
    const int j  = blockIdx.x;            // g-pair: g = 2j, 2j+1
    const int bt = blockIdx.y;
    const int b  = bt >> 4, t = bt & 15;
    const int f  = threadIdx.x;
    __shared__ float ldec[16][64];        // 16 q x 64 ch (this g-pair)

    const float* decbt = dec + (size_t)b * 65536 + (size_t)t * 256 + j * 64;
    {
        const int q = threadIdx.x >> 4, seg = threadIdx.x & 15;
        const float4 v = *reinterpret_cast<const float4*>(decbt + q * 4096 + seg * 4);
        *reinterpret_cast<float4*>(&ldec[q][seg * 4]) = v;
    }
    __syncthreads();

    u16x8 rv[8];
    #pragma unroll
    for (int gi = 0; gi < 2; ++gi) {
        const int g = j * 2 + gi;
        float wv[16];
        #pragma unroll
        for (int q = 0; q < 16; ++q) wv[q] = W[(q * 8 + g) * FF + f];   // coalesced
        #pragma unroll
        for (int cc = 0; cc < 32; ++cc) {
            float s = 0.f;
            #pragma unroll
            for (int q = 0; q < 16; ++q) s += ldec[q][gi * 32 + cc] * wv[q];
            const int idx = gi * 32 + cc;
            rv[idx >> 3][idx & 7] = f2bf(s);
        }
    }
    unsigned short* dst = Mt + (size_t)bt * (FF * CCH) + (size_t)f * CCH + j * 64;
    #pragma unroll
    for (int s = 0; s < 8; ++s)
        *reinterpret_cast<u16x8*>(dst + s * 8) = rv[s];   // 128 B/thread contiguous
}

// ---------------- Phase 2: tiled MFMA GEMM, 256 rows x 128 f per block ----------------
// 1024 blocks x 512 thr (8 waves). Each wave: 32 rows x 128 f, 8 k-steps.
__global__ __launch_bounds__(512, 4) void gemm_tile_kernel(
        const float* __restrict__ E, const unsigned short* __restrict__ Mt,
        const float* __restrict__ bias, float* __restrict__ O) {
    const int id0 = blockIdx.x;                       // 0..1023
    const int id  = ((id0 & 7) << 7) | (id0 >> 3);    // XCD-chunked bijection
    const int bt = id >> 3;                           // 8 ids per bt
    const int fh = (id >> 2) & 1;                     // 128-f half
    const int rg = id & 3;                            // 256-row group
    const int tid = threadIdx.x;
    const int lane = tid & 63, wq = tid >> 6;         // wq 0..7
    const int lr5 = lane & 31, kgr = lane >> 5;

    const float*          Ebt = E  + (size_t)bt * (HW * CCH);
    const unsigned short* Mtb = Mt + (size_t)bt * (FF * CCH) + (size_t)(fh * 128) * CCH;
    float*                Obt = O  + (size_t)bt * (HW * FF);

    // Bs layout (R15): [half: k<128 | k>=128][row 0..127][16 slots of 16B]
    __shared__ __align__(16) unsigned short Bs[128 * 256];  // 64 KB, shared by 8 waves
    __shared__ __align__(16) unsigned short Et[8][32 * 32]; // 8 x 2KB wave-private

    const int rowbase = rg * 256 + wq * 32;
    const int g_r8 = lane >> 3;                       // staging row-in-8
    const int g_s3 = lane & 7;                        // staging 16B slot
    const int bswz = lr5 & 7;                         // Bs read swizzle
    const int eswz = lr5 & 3;                         // E-tile read swizzle

    unsigned short* Etw = &Et[wq][0];
    const unsigned short* Etr = &Etw[lr5 * 32];

    f32x4 Sva[4], Svb[4];
    f32x16 acc0, acc1, acc2, acc3;

    auto GLOAD = [&](int it, f32x4 (&S)[4]) {         // full 128B-line loads
        const float* base = Ebt + (size_t)rowbase * CCH + (it & 7) * 32 + g_s3 * 4;
        #pragma unroll
        for (int i = 0; i < 4; ++i)
            S[i] = *reinterpret_cast<const f32x4*>(base + (size_t)(i * 8 + g_r8) * CCH);
    };

    // ---- prologue: E loads FIRST (oldest), then Bs half1, then half2 ----
    GLOAD(0, Sva);
    GLOAD(1, Svb);
    __builtin_amdgcn_sched_barrier(0);                // pin: E before half1
    #pragma unroll
    for (int p = 0; p < 4; ++p) {                     // half1: k < 128
        const int g = p * 512 + tid;                  // 0..2047 -> h=0
        const int r = (g & 2047) >> 4, s16 = g & 15;
        gload_lds16(Mtb + (size_t)r * CCH + ((s16 ^ (r & 7)) * 8), &Bs[g * 8]);
    }
    __builtin_amdgcn_sched_barrier(0);                // pin: half1 before half2
    #pragma unroll
    for (int p = 4; p < 8; ++p) {                     // half2: k >= 128
        const int g = p * 512 + tid;                  // 2048..4095 -> h=1
        const int r = (g & 2047) >> 4, s16 = g & 15;
        gload_lds16(Mtb + (size_t)r * CCH + (16 + (s16 ^ (r & 7))) * 8, &Bs[g * 8]);
    }
    __builtin_amdgcn_sched_barrier(0);
    // wait: E(8) + half1(4) retired; half2(4) may stay in flight
    asm volatile("s_waitcnt vmcnt(4)" ::: "memory");
    __builtin_amdgcn_s_barrier();

    float bv[4];
    #pragma unroll
    for (int fn = 0; fn < 4; ++fn) bv[fn] = bias[fh * 128 + fn * 32 + lr5];

    const unsigned short* Bsp0[4];                    // half1 row bases
    const unsigned short* Bsp1[4];                    // half2 row bases
    #pragma unroll
    for (int fn = 0; fn < 4; ++fn) {
        const int row = fn * 32 + lr5;
        Bsp0[fn] = &Bs[row * 128];
        Bsp1[fn] = &Bs[16384 + row * 128];
    }

    auto EWRITE = [&](const f32x4 (&S)[4]) {          // cvt + swizzled ds_write_b64
        #pragma unroll
        for (int i = 0; i < 4; ++i) {
            const int r = i * 8 + g_r8;
            u16x4 h = { f2bf(S[i][0]), f2bf(S[i][1]), f2bf(S[i][2]), f2bf(S[i][3]) };
            *reinterpret_cast<u16x4*>(
                &Etw[r * 32 + (((g_s3 >> 1) ^ (r & 3)) * 8) + (g_s3 & 1) * 4]) = h;
        }
    };
    auto COMPUTE = [&](int it) {
        const int kc = it & 7;
        if (kc == 0) {
            acc0 = (f32x16)0.f; acc1 = (f32x16)0.f;
            acc2 = (f32x16)0.f; acc3 = (f32x16)0.f;
        }
        #pragma unroll
        for (int kk = 0; kk < 2; ++kk) {
            const bf16x8 af = *reinterpret_cast<const bf16x8*>(
                &Etr[((kk * 2 + kgr) ^ eswz) * 8]);
            // slot within half: ((kc&3)*4 + kk*2 + kgr) ^ bswz; half = kc>=4
            const int bo = ((((kc & 3) * 4 + kk * 2 + kgr) ^ bswz)) * 8;
            const unsigned short* const* Bsp = (kc < 4) ? Bsp0 : Bsp1;
            acc0 = __builtin_amdgcn_mfma_f32_32x32x16_bf16(
                af, *reinterpret_cast<const bf16x8*>(&Bsp[0][bo]), acc0, 0, 0, 0);
            acc1 = __builtin_amdgcn_mfma_f32_32x32x16_bf16(
                af, *reinterpret_cast<const bf16x8*>(&Bsp[1][bo]), acc1, 0, 0, 0);
            acc2 = __builtin_amdgcn_mfma_f32_32x32x16_bf16(
                af, *reinterpret_cast<const bf16x8*>(&Bsp[2][bo]), acc2, 0, 0, 0);
            acc3 = __builtin_amdgcn_mfma_f32_32x32x16_bf16(
                af, *reinterpret_cast<const bf16x8*>(&Bsp[3][bo]), acc3, 0, 0, 0);
        }
        if (kc == 7) {
            // C/D: col = lane&31, row = (reg&3) + 8*(reg>>2) + 4*(lane>>5)
            const int row0 = rowbase + 4 * kgr;
            #pragma unroll
            for (int reg = 0; reg < 16; ++reg) {
                const int r = row0 + (reg & 3) + 8 * (reg >> 2);
                float* op = Obt + (size_t)r * FF + fh * 128 + lr5;
                __builtin_nontemporal_store(fmaxf(acc0[reg] + bv[0], 0.f), op);
                __builtin_nontemporal_store(fmaxf(acc1[reg] + bv[1], 0.f), op + 32);
                __builtin_nontemporal_store(fmaxf(acc2[reg] + bv[2], 0.f), op + 64);
                __builtin_nontemporal_store(fmaxf(acc3[reg] + bv[3], 0.f), op + 96);
            }
        }
    };

    EWRITE(Sva);                      // tile <- it 0 (E data retired by vmcnt(4))
    for (int itp = 0; itp < 8; itp += 2) {
        COMPUTE(itp);                 // reads tile(itp); kc<4 -> Bs half1
        if (itp + 2 < 8) GLOAD(itp + 2, Sva);
        EWRITE(Svb);                  // tile <- itp+1 (after reads of itp)
        COMPUTE(itp + 1);
        if (itp + 3 < 8) GLOAD(itp + 3, Svb);
        if (itp + 2 < 8) EWRITE(Sva); // tile <- itp+2
    }
}

extern "C" void kernel_launch(void* const* d_in, const int* in_sizes, int n_in,
                              void* d_out, int out_size, void* d_ws, size_t ws_size,
                              hipStream_t stream) {
    const float* dec  = (const float*)d_in[0];   // (8, 256, 256)
    const float* enc  = (const float*)d_in[1];   // (8, 16, 32, 32, 256)
    const float* W    = (const float*)d_in[2];   // (128, 256)
    const float* bias = (const float*)d_in[3];   // (256,)
    float* out = (float*)d_out;                  // (8, 16, 32, 32, 256) fp32
    unsigned short* Mt = (unsigned short*)d_ws;  // 128*256*256*2 = 16.8 MB bf16

    compute_Mt_kernel<<<dim3(4, 128), dim3(256), 0, stream>>>(dec, W, Mt);
    gemm_tile_kernel<<<dim3(1024), dim3(512), 0, stream>>>(enc, Mt, bias, out);
}